// Round 3
// 751.791 us; speedup vs baseline: 1.1468x; 1.1468x over previous
//
#include <hip/hip_runtime.h>
#include <hip/hip_bf16.h>
#include <stdint.h>

#define TOKENS 4096
#define IN_F   4096
#define OUT_F  11008
#define NGROUPS 32

typedef __bf16 bf16_t;
typedef __bf16 bf16x4 __attribute__((ext_vector_type(4)));
typedef __bf16 bf16x8 __attribute__((ext_vector_type(8)));
typedef float  f32x4  __attribute__((ext_vector_type(4)));

// ---------------- pre-pass: x fp32 -> bf16 (16B load, 8B store per thread) ----
__global__ __launch_bounds__(256)
void cvt_x_kernel(const float* __restrict__ x, bf16_t* __restrict__ xb) {
    int v = blockIdx.x * 256 + threadIdx.x;          // one float4 per thread
    float4 a = ((const float4*)x)[v];
    bf16x4 o;
    o[0] = (bf16_t)a.x; o[1] = (bf16_t)a.y; o[2] = (bf16_t)a.z; o[3] = (bf16_t)a.w;
    ((bf16x4*)xb)[v] = o;
}

// ---------------- pre-pass: W int32 -> bf16 * group-scale ----------------
__global__ __launch_bounds__(256)
void dequant_w_kernel(const int* __restrict__ w, const float* __restrict__ scale,
                      bf16_t* __restrict__ wb) {
    int v = blockIdx.x * 256 + threadIdx.x;          // one int4 (4 weights) per thread
    int4 a = ((const int4*)w)[v];
    // element base = 4v: o = 4v>>12 = v>>10 ; g = ((4v)&4095)>>7 = (v&1023)>>5
    float s = scale[(v >> 10) * NGROUPS + ((v & 1023) >> 5)];
    bf16x4 o;
    o[0] = (bf16_t)((float)a.x * s);
    o[1] = (bf16_t)((float)a.y * s);
    o[2] = (bf16_t)((float)a.z * s);
    o[3] = (bf16_t)((float)a.w * s);
    ((bf16x4*)wb)[v] = o;
}

// ---------------- GEMM: C = A[M,K] * B[N,K]^T + bias ----------------
// 256x256 tile, BK=32, 8 waves (2M x 4N), wave tile 128x64.
// LDS: ring of 4 K-chunk slots per matrix (4 x 16 KiB x 2 = 128 KiB), depth-3
// prefetch. Counted vmcnt(6) in-loop (never 0); 2 phases/chunk; setprio around
// MFMA clusters; stages issued only AFTER a barrier so ring-slot reuse is
// inductively ordered behind all waves' drained ds_reads.
#define BM 256
#define BN 256
#define BK 32
#define NCH   (IN_F / BK)    // 128
#define SLOTE (BM * BK)      // 8192 bf16 = 16 KiB per ring slot
#define NT_M  (TOKENS / BM)  // 16
#define NT_N  (OUT_F / BN)   // 43

__device__ __forceinline__ void async16(const void* g, void* l) {
    __builtin_amdgcn_global_load_lds(
        (const __attribute__((address_space(1))) uint32_t*)g,
        (__attribute__((address_space(3))) uint32_t*)l, 16, 0, 0);
}

__global__ __launch_bounds__(512, 2)
void gemm_bt_kernel(const bf16_t* __restrict__ A,
                    const bf16_t* __restrict__ B,
                    const float* __restrict__ bias,
                    float* __restrict__ C) {
    __shared__ __align__(16) bf16_t sA[4 * SLOTE];
    __shared__ __align__(16) bf16_t sB[4 * SLOTE];

    // ---- XCD swizzle: 688 blocks = 8 XCD x 86. Each XCD owns 2 M-panels
    // (2x2 MB of A = its whole L2, resident for all 43 N-tiles) and walks
    // N-tiles n-major (mlocal inner) so the B panel is shared by the pair.
    const int lin    = blockIdx.x;
    const int xcd    = lin & 7;
    const int idx    = lin >> 3;          // 0..85
    const int mlocal = idx & 1;
    const int nt     = idx >> 1;          // 0..42
    const int bm     = (xcd * 2 + mlocal) * BM;
    const int bn     = nt * BN;

    const int tid    = threadIdx.x;
    const int lane   = tid & 63;
    const int wave   = tid >> 6;          // 0..7
    const int wm     = wave >> 2;         // 0..1 -> A half (rows wm*128..+127)
    const int wn     = wave & 3;          // 0..3 -> B quarter (rows wn*64..+63)
    const int lane15 = lane & 15;
    const int quad   = lane >> 4;
    // bank swizzle: slot row = 64B = 4 x 16B chunks; phys chunk = quad ^ ((row>>1)&3).
    // Row bases (wm*128, wn*64, i*16) are 0 mod 16, so the term is lane-only.
    // Conflict-free: row stride 64B shifts odd rows by 16 banks, so 8 consecutive
    // lanes hit 8 distinct 16B bank groups.
    const int swq    = quad ^ ((lane15 >> 1) & 3);

    // fragment LDS element offsets within a slot (A: 8 M-frags, B: 4 N-frags)
    int aoff[8], boff[4];
    #pragma unroll
    for (int i = 0; i < 8; ++i) {
        int mr = wm * 128 + i * 16 + lane15;
        aoff[i] = mr * BK + swq * 8;
    }
    #pragma unroll
    for (int t = 0; t < 4; ++t) {
        int nr = wn * 64 + t * 16 + lane15;
        boff[t] = nr * BK + swq * 8;
    }

    // staging geometry: LDS 16B-chunk s = part*512 + tid -> row r = s>>2,
    // phys col16 = s&3, logical k-chunk = (s&3) ^ ((r>>1)&3) (inverse of read swz,
    // which reduces to (tid&3) ^ ((tid>>3)&3) since part*128 is 0 mod 8).
    const int r0   = tid >> 2;                          // 0..127
    const int qlog = (tid & 3) ^ ((tid >> 3) & 3);
    const bf16_t* gA0 = A + (size_t)(bm + r0) * IN_F + qlog * 8;
    const bf16_t* gA1 = A + (size_t)(bm + 128 + r0) * IN_F + qlog * 8;
    const bf16_t* gB0 = B + (size_t)(bn + r0) * IN_F + qlog * 8;
    const bf16_t* gB1 = B + (size_t)(bn + 128 + r0) * IN_F + qlog * 8;
    const int ldsP0 = wave * 512;           // wave-uniform dest (elems), part 0
    const int ldsP1 = 4096 + wave * 512;    // part 1

    f32x4 acc[8][4] = {};

    // prologue: stage chunks 0,1,2; wait for chunk 0 (8 = chunks 1,2 in flight)
    #pragma unroll
    for (int c = 0; c < 3; ++c) {
        async16(gA0 + c * BK, sA + c * SLOTE + ldsP0);
        async16(gA1 + c * BK, sA + c * SLOTE + ldsP1);
        async16(gB0 + c * BK, sB + c * SLOTE + ldsP0);
        async16(gB1 + c * BK, sB + c * SLOTE + ldsP1);
    }
    asm volatile("s_waitcnt vmcnt(8)" ::: "memory");
    __builtin_amdgcn_s_barrier();

    // main loop: uniform (tail staged as clamped dummy chunks so vmcnt(6)
    // stays exact). At the phase-B wait, the 6 newest outstanding loads are
    // {A-pair(j+2), B-pair(j+1), A-pair(j+1)} -> own chunk j+1 fully landed
    // before the barrier; the barrier rendezvous extends this to all waves.
    for (int j = 0; j < NCH; ++j) {
        const int slot = j & 3;
        const bf16_t* sAs = sA + slot * SLOTE;
        const bf16_t* sBs = sB + slot * SLOTE;
        const int cs   = j + 3;
        const int kpre = (cs < NCH ? cs : NCH - 1) * BK;   // clamp: dummy refetch
        bf16_t* dA = sA + (cs & 3) * SLOTE;
        bf16_t* dB = sB + (cs & 3) * SLOTE;

        bf16x8 aF[4], bF[4];
        #pragma unroll
        for (int t = 0; t < 4; ++t) bF[t] = *(const bf16x8*)(sBs + boff[t]);
        #pragma unroll
        for (int t = 0; t < 4; ++t) aF[t] = *(const bf16x8*)(sAs + aoff[t]);

        // ---- phase A: barrier -> drain own LDS reads -> issue A-prefetch -> 16 MFMA
        __builtin_amdgcn_s_barrier();
        asm volatile("s_waitcnt lgkmcnt(0)" ::: "memory");
        __builtin_amdgcn_sched_barrier(0);
        // WAR-safe: every wave drained its reads of slot (cs&3)==((j-1)&3) at its
        // post-barrier-B lgkmcnt(0) of iter j-1 before reaching the barrier above
        async16(gA0 + kpre, dA + ldsP0);
        async16(gA1 + kpre, dA + ldsP1);

        __builtin_amdgcn_s_setprio(1);
        #pragma unroll
        for (int i = 0; i < 4; ++i)
            #pragma unroll
            for (int t = 0; t < 4; ++t)
                acc[i][t] = __builtin_amdgcn_mfma_f32_16x16x32_bf16(
                    aF[i], bF[t], acc[i][t], 0, 0, 0);
        __builtin_amdgcn_s_setprio(0);

        // ---- phase B: rows 64..127 of the wave tile, reuse bF
        #pragma unroll
        for (int t = 0; t < 4; ++t) aF[t] = *(const bf16x8*)(sAs + aoff[4 + t]);

        asm volatile("s_waitcnt vmcnt(6)" ::: "memory");
        __builtin_amdgcn_s_barrier();
        asm volatile("s_waitcnt lgkmcnt(0)" ::: "memory");
        __builtin_amdgcn_sched_barrier(0);
        async16(gB0 + kpre, dB + ldsP0);
        async16(gB1 + kpre, dB + ldsP1);

        __builtin_amdgcn_s_setprio(1);
        #pragma unroll
        for (int i = 0; i < 4; ++i)
            #pragma unroll
            for (int t = 0; t < 4; ++t)
                acc[4 + i][t] = __builtin_amdgcn_mfma_f32_16x16x32_bf16(
                    aF[i], bF[t], acc[4 + i][t], 0, 0, 0);
        __builtin_amdgcn_s_setprio(0);
    }

    // drain dummy prefetches: no global_load_lds may be in flight when this
    // block retires (a successor block reusing this CU's LDS could be corrupted)
    asm volatile("s_waitcnt vmcnt(0)" ::: "memory");

    // epilogue: C/D layout col=lane&15, row=quad*4+reg (m89/m91-verified)
    #pragma unroll
    for (int t = 0; t < 4; ++t) {
        const int n = bn + wn * 64 + t * 16 + lane15;
        const float bj = bias[n];
        #pragma unroll
        for (int i = 0; i < 8; ++i) {
            const int m0 = bm + wm * 128 + i * 16 + quad * 4;
            #pragma unroll
            for (int r = 0; r < 4; ++r)
                C[(size_t)(m0 + r) * OUT_F + n] = acc[i][t][r] + bj;
        }
    }
}

extern "C" void kernel_launch(void* const* d_in, const int* in_sizes, int n_in,
                              void* d_out, int out_size, void* d_ws, size_t ws_size,
                              hipStream_t stream) {
    const float* x     = (const float*)d_in[0];
    const int*   w     = (const int*)d_in[1];
    const float* scale = (const float*)d_in[2];
    const float* bias  = (const float*)d_in[3];
    float* out = (float*)d_out;

    // workspace: [x_bf16 : 33,554,432 B][w_bf16 : 90,177,536 B]
    bf16_t* xb = (bf16_t*)d_ws;
    bf16_t* wb = (bf16_t*)((char*)d_ws + (size_t)TOKENS * IN_F * 2);

    cvt_x_kernel<<<TOKENS * IN_F / (4 * 256), 256, 0, stream>>>(x, xb);
    dequant_w_kernel<<<OUT_F * IN_F / (4 * 256), 256, 0, stream>>>(w, scale, wb);

    gemm_bt_kernel<<<NT_M * NT_N, 512, 0, stream>>>(xb, wb, bias, out);
}